// Round 3
// baseline (3585.740 us; speedup 1.0000x reference)
//
#include <hip/hip_runtime.h>
#include <math.h>

// SSRNet constants
#define BB   16384   // batch
#define FF   64      // fields
#define EE   16      // embedding dim
#define GG   16      // groups
#define DD   256     // d_mid_cols
#define GD   4096    // GG*DD
#define EPSV 1e-3f

// Round-2 post-mortem: core dump (GPU memory fault) most likely from d_ws
// overrun (576MB fp32 layout). This round: 160MB layout (bf16 xflat+h1,
// h2 eliminated by fusing group-mean + head into block2) + ws_size guard.

__device__ __forceinline__ float gelu_f(float x) {
    // exact gelu (approximate=False): 0.5*x*(1+erf(x/sqrt(2)))
    return 0.5f * x * (1.0f + erff(x * 0.70710678118654752f));
}

// bf16 helpers (exact RNE pack, exact unpack)
__device__ __forceinline__ unsigned short f2bf(float f) {
    unsigned x = __float_as_uint(f);
    return (unsigned short)((x + 0x7fffu + ((x >> 16) & 1u)) >> 16);
}
__device__ __forceinline__ float bf2f(unsigned short u) {
    return __uint_as_float(((unsigned)u) << 16);
}
__device__ __forceinline__ unsigned int pk2(float a, float b) {
    return (unsigned)f2bf(a) | ((unsigned)f2bf(b) << 16);
}

// ---------------------------------------------------------------------------
// Kernel 1: emb = table[feat_index] * feat_value ; LN over E=16 -> bf16 xflat
// One thread per (b,f) row of 16 elements. xflat[b][f*16+e], bf16.
// ---------------------------------------------------------------------------
__global__ __launch_bounds__(256)
void embed_ln_kernel(const int* __restrict__ fidx,
                     const float* __restrict__ fval,
                     const float* __restrict__ table,
                     const float* __restrict__ gamma,
                     const float* __restrict__ beta,
                     unsigned short* __restrict__ xflat) {
    const int t = blockIdx.x * blockDim.x + threadIdx.x;   // 0 .. B*F-1 (exact grid)
    const int row = fidx[t];
    const float v = fval[t];
    const float4* src = reinterpret_cast<const float4*>(table) + (size_t)row * 4;
    float4 e0 = src[0], e1 = src[1], e2 = src[2], e3 = src[3];
    float x[16] = {e0.x,e0.y,e0.z,e0.w, e1.x,e1.y,e1.z,e1.w,
                   e2.x,e2.y,e2.z,e2.w, e3.x,e3.y,e3.z,e3.w};
    float s = 0.f;
    #pragma unroll
    for (int j = 0; j < 16; ++j) { x[j] *= v; s += x[j]; }
    const float mu = s * (1.0f/16.0f);
    float q = 0.f;
    #pragma unroll
    for (int j = 0; j < 16; ++j) { float d = x[j] - mu; q += d*d; }
    const float sc = rsqrtf(q * (1.0f/16.0f) + EPSV);
    float o[16];
    #pragma unroll
    for (int j = 0; j < 16; ++j) o[j] = (x[j] - mu) * sc * gamma[j] + beta[j];
    uint4 p0, p1;
    p0.x = pk2(o[0], o[1]);  p0.y = pk2(o[2], o[3]);
    p0.z = pk2(o[4], o[5]);  p0.w = pk2(o[6], o[7]);
    p1.x = pk2(o[8], o[9]);  p1.y = pk2(o[10], o[11]);
    p1.z = pk2(o[12], o[13]); p1.w = pk2(o[14], o[15]);
    uint4* dst = reinterpret_cast<uint4*>(xflat) + (size_t)t * 2;
    dst[0] = p0;
    dst[1] = p1;
}

// ---------------------------------------------------------------------------
// Kernel 2: SSR block 1. grid = (B/64, G), 256 threads, 144KB LDS (1 blk/CU).
// in: xflat bf16 [B,1024]; out: h1 bf16 [B,4096].
// Thread micro-tile: 8 rows x 8 cols fp32.
// ---------------------------------------------------------------------------
__global__ __launch_bounds__(256, 1)
void ssr_block1_kernel(const unsigned short* __restrict__ xin,  // [B,1024] bf16
                       const int* __restrict__ idx,             // [G, D]
                       const float* __restrict__ Wmat,          // [G, 2, D, D]
                       const float* __restrict__ bias,          // [G, 2, D]
                       const float* __restrict__ gam,           // [G, D]
                       const float* __restrict__ bet,           // [G, D]
                       unsigned short* __restrict__ h1) {       // [B, 4096] bf16
    __shared__ float xg[64][DD];
    __shared__ float hb[64][DD];
    __shared__ float wc[16][DD];

    const int g  = blockIdx.y;
    const int b0 = blockIdx.x * 64;
    const int t  = threadIdx.x;

    // gather: xg[r][t] = xin[b0+r][idx[g][t]]
    {
        const int col = idx[g*DD + t];
        #pragma unroll 4
        for (int r = 0; r < 64; ++r)
            xg[r][t] = bf2f(xin[(size_t)(b0 + r) * 1024 + col]);
    }

    const int ct = t & 31;   // cols ct*8..+7
    const int rt = t >> 5;   // rows rt*8..+7
    float acc[8][8];

    for (int l = 0; l < 2; ++l) {
        const float* __restrict__ Wg = Wmat + ((size_t)g*2 + l) * DD * DD;
        const float* __restrict__ bg = bias + ((size_t)g*2 + l) * DD;
        const float* __restrict__ in = (l == 0) ? &xg[0][0] : &hb[0][0];

        const float4 bl = *reinterpret_cast<const float4*>(bg + ct*8);
        const float4 bh = *reinterpret_cast<const float4*>(bg + ct*8 + 4);
        #pragma unroll
        for (int i = 0; i < 8; ++i) {
            acc[i][0]=bl.x; acc[i][1]=bl.y; acc[i][2]=bl.z; acc[i][3]=bl.w;
            acc[i][4]=bh.x; acc[i][5]=bh.y; acc[i][6]=bh.z; acc[i][7]=bh.w;
        }

        for (int kc = 0; kc < DD; kc += 16) {
            __syncthreads();
            #pragma unroll
            for (int qq = 0; qq < 4; ++qq) {
                const int e4  = qq*256 + t;
                const int wr  = e4 >> 6;
                const int wc4 = e4 & 63;
                reinterpret_cast<float4*>(&wc[wr][0])[wc4] =
                    reinterpret_cast<const float4*>(Wg + (size_t)(kc + wr) * DD)[wc4];
            }
            __syncthreads();

            #pragma unroll
            for (int dk = 0; dk < 16; dk += 4) {
                float4 xv[8];
                #pragma unroll
                for (int i = 0; i < 8; ++i)
                    xv[i] = *reinterpret_cast<const float4*>(in + (rt*8 + i)*DD + kc + dk);
                float4 wl[4], wh[4];
                #pragma unroll
                for (int m = 0; m < 4; ++m) {
                    wl[m] = *reinterpret_cast<const float4*>(&wc[dk + m][ct*8]);
                    wh[m] = *reinterpret_cast<const float4*>(&wc[dk + m][ct*8 + 4]);
                }
                #pragma unroll
                for (int m = 0; m < 4; ++m) {
                    const float4 w0 = wl[m];
                    const float4 w1 = wh[m];
                    #pragma unroll
                    for (int i = 0; i < 8; ++i) {
                        const float a = (m==0) ? xv[i].x : (m==1) ? xv[i].y
                                       : (m==2) ? xv[i].z : xv[i].w;
                        acc[i][0] = fmaf(a, w0.x, acc[i][0]);
                        acc[i][1] = fmaf(a, w0.y, acc[i][1]);
                        acc[i][2] = fmaf(a, w0.z, acc[i][2]);
                        acc[i][3] = fmaf(a, w0.w, acc[i][3]);
                        acc[i][4] = fmaf(a, w1.x, acc[i][4]);
                        acc[i][5] = fmaf(a, w1.y, acc[i][5]);
                        acc[i][6] = fmaf(a, w1.z, acc[i][6]);
                        acc[i][7] = fmaf(a, w1.w, acc[i][7]);
                    }
                }
            }
        }

        if (l == 0) {
            #pragma unroll
            for (int i = 0; i < 8; ++i) {
                float4 o0, o1;
                o0.x = gelu_f(acc[i][0]); o0.y = gelu_f(acc[i][1]);
                o0.z = gelu_f(acc[i][2]); o0.w = gelu_f(acc[i][3]);
                o1.x = gelu_f(acc[i][4]); o1.y = gelu_f(acc[i][5]);
                o1.z = gelu_f(acc[i][6]); o1.w = gelu_f(acc[i][7]);
                *reinterpret_cast<float4*>(&hb[rt*8 + i][ct*8])     = o0;
                *reinterpret_cast<float4*>(&hb[rt*8 + i][ct*8 + 4]) = o1;
            }
        }
    }

    // epilogue: res = gelu(acc)+xg; LN over D; write bf16
    const float* gamp = gam + g*DD + ct*8;
    const float* betp = bet + g*DD + ct*8;
    const float4 ga0 = *reinterpret_cast<const float4*>(gamp);
    const float4 ga1 = *reinterpret_cast<const float4*>(gamp + 4);
    const float4 bt0 = *reinterpret_cast<const float4*>(betp);
    const float4 bt1 = *reinterpret_cast<const float4*>(betp + 4);

    #pragma unroll
    for (int i = 0; i < 8; ++i) {
        const int r = rt*8 + i;
        const float4 x0 = *reinterpret_cast<const float4*>(&xg[r][ct*8]);
        const float4 x1 = *reinterpret_cast<const float4*>(&xg[r][ct*8 + 4]);
        float v0 = gelu_f(acc[i][0]) + x0.x;
        float v1 = gelu_f(acc[i][1]) + x0.y;
        float v2 = gelu_f(acc[i][2]) + x0.z;
        float v3 = gelu_f(acc[i][3]) + x0.w;
        float v4 = gelu_f(acc[i][4]) + x1.x;
        float v5 = gelu_f(acc[i][5]) + x1.y;
        float v6 = gelu_f(acc[i][6]) + x1.z;
        float v7 = gelu_f(acc[i][7]) + x1.w;

        float s = ((v0 + v1) + (v2 + v3)) + ((v4 + v5) + (v6 + v7));
        #pragma unroll
        for (int mm = 1; mm < 32; mm <<= 1) s += __shfl_xor(s, mm);
        const float mu = s * (1.0f/256.0f);

        float q = (v0-mu)*(v0-mu) + (v1-mu)*(v1-mu) + (v2-mu)*(v2-mu) + (v3-mu)*(v3-mu)
                + (v4-mu)*(v4-mu) + (v5-mu)*(v5-mu) + (v6-mu)*(v6-mu) + (v7-mu)*(v7-mu);
        #pragma unroll
        for (int mm = 1; mm < 32; mm <<= 1) q += __shfl_xor(q, mm);
        const float sc = rsqrtf(q * (1.0f/256.0f) + EPSV);

        uint4 pk;
        pk.x = pk2((v0-mu)*sc*ga0.x + bt0.x, (v1-mu)*sc*ga0.y + bt0.y);
        pk.y = pk2((v2-mu)*sc*ga0.z + bt0.z, (v3-mu)*sc*ga0.w + bt0.w);
        pk.z = pk2((v4-mu)*sc*ga1.x + bt1.x, (v5-mu)*sc*ga1.y + bt1.y);
        pk.w = pk2((v6-mu)*sc*ga1.z + bt1.z, (v7-mu)*sc*ga1.w + bt1.w);
        *reinterpret_cast<uint4*>(h1 + (size_t)(b0 + r) * GD + g*DD + ct*8) = pk;
    }
}

// ---------------------------------------------------------------------------
// Kernel 3: SSR block 2 + group-mean + head, fused. grid = B/64, 256 threads.
// Loops all 16 groups; acc_ssr (registers) accumulates the group mean; head
// (256->64 relu, 64->1 sigmoid) computed in-block reusing dead LDS.
// ---------------------------------------------------------------------------
__global__ __launch_bounds__(256, 1)
void ssr_block2_head_kernel(const unsigned short* __restrict__ h1, // [B,4096] bf16
                            const int* __restrict__ idx,           // [G, D]
                            const float* __restrict__ Wmat,        // [G, 2, D, D]
                            const float* __restrict__ bias,        // [G, 2, D]
                            const float* __restrict__ gam,         // [G, D]
                            const float* __restrict__ bet,         // [G, D]
                            const float* __restrict__ Wp1,         // [D, 64]
                            const float* __restrict__ bp1,         // [64]
                            const float* __restrict__ Wp2,         // [64]
                            const float* __restrict__ bp2,         // [1]
                            float* __restrict__ outp) {            // [B]
    __shared__ float xg[64][DD];
    __shared__ float hb[64][DD];
    __shared__ float wc[16][DD];

    const int b0 = blockIdx.x * 64;
    const int t  = threadIdx.x;
    const int ct = t & 31;
    const int rt = t >> 5;

    float acc_ssr[8][8];
    #pragma unroll
    for (int i = 0; i < 8; ++i)
        #pragma unroll
        for (int q = 0; q < 8; ++q) acc_ssr[i][q] = 0.f;

    float acc[8][8];

    for (int g = 0; g < GG; ++g) {
        __syncthreads();   // prev group's epilogue xg reads done
        {
            const int col = idx[g*DD + t];
            #pragma unroll 4
            for (int r = 0; r < 64; ++r)
                xg[r][t] = bf2f(h1[(size_t)(b0 + r) * GD + col]);
        }

        for (int l = 0; l < 2; ++l) {
            const float* __restrict__ Wg = Wmat + ((size_t)g*2 + l) * DD * DD;
            const float* __restrict__ bg = bias + ((size_t)g*2 + l) * DD;
            const float* __restrict__ in = (l == 0) ? &xg[0][0] : &hb[0][0];

            const float4 bl = *reinterpret_cast<const float4*>(bg + ct*8);
            const float4 bh = *reinterpret_cast<const float4*>(bg + ct*8 + 4);
            #pragma unroll
            for (int i = 0; i < 8; ++i) {
                acc[i][0]=bl.x; acc[i][1]=bl.y; acc[i][2]=bl.z; acc[i][3]=bl.w;
                acc[i][4]=bh.x; acc[i][5]=bh.y; acc[i][6]=bh.z; acc[i][7]=bh.w;
            }

            for (int kc = 0; kc < DD; kc += 16) {
                __syncthreads();
                #pragma unroll
                for (int qq = 0; qq < 4; ++qq) {
                    const int e4  = qq*256 + t;
                    const int wr  = e4 >> 6;
                    const int wc4 = e4 & 63;
                    reinterpret_cast<float4*>(&wc[wr][0])[wc4] =
                        reinterpret_cast<const float4*>(Wg + (size_t)(kc + wr) * DD)[wc4];
                }
                __syncthreads();

                #pragma unroll
                for (int dk = 0; dk < 16; dk += 4) {
                    float4 xv[8];
                    #pragma unroll
                    for (int i = 0; i < 8; ++i)
                        xv[i] = *reinterpret_cast<const float4*>(in + (rt*8 + i)*DD + kc + dk);
                    float4 wl[4], wh[4];
                    #pragma unroll
                    for (int m = 0; m < 4; ++m) {
                        wl[m] = *reinterpret_cast<const float4*>(&wc[dk + m][ct*8]);
                        wh[m] = *reinterpret_cast<const float4*>(&wc[dk + m][ct*8 + 4]);
                    }
                    #pragma unroll
                    for (int m = 0; m < 4; ++m) {
                        const float4 w0 = wl[m];
                        const float4 w1 = wh[m];
                        #pragma unroll
                        for (int i = 0; i < 8; ++i) {
                            const float a = (m==0) ? xv[i].x : (m==1) ? xv[i].y
                                           : (m==2) ? xv[i].z : xv[i].w;
                            acc[i][0] = fmaf(a, w0.x, acc[i][0]);
                            acc[i][1] = fmaf(a, w0.y, acc[i][1]);
                            acc[i][2] = fmaf(a, w0.z, acc[i][2]);
                            acc[i][3] = fmaf(a, w0.w, acc[i][3]);
                            acc[i][4] = fmaf(a, w1.x, acc[i][4]);
                            acc[i][5] = fmaf(a, w1.y, acc[i][5]);
                            acc[i][6] = fmaf(a, w1.z, acc[i][6]);
                            acc[i][7] = fmaf(a, w1.w, acc[i][7]);
                        }
                    }
                }
            }

            if (l == 0) {
                #pragma unroll
                for (int i = 0; i < 8; ++i) {
                    float4 o0, o1;
                    o0.x = gelu_f(acc[i][0]); o0.y = gelu_f(acc[i][1]);
                    o0.z = gelu_f(acc[i][2]); o0.w = gelu_f(acc[i][3]);
                    o1.x = gelu_f(acc[i][4]); o1.y = gelu_f(acc[i][5]);
                    o1.z = gelu_f(acc[i][6]); o1.w = gelu_f(acc[i][7]);
                    *reinterpret_cast<float4*>(&hb[rt*8 + i][ct*8])     = o0;
                    *reinterpret_cast<float4*>(&hb[rt*8 + i][ct*8 + 4]) = o1;
                }
            }
        }

        // epilogue: LN(gelu(acc)+xg) -> acc_ssr += o/16
        const float* gamp = gam + g*DD + ct*8;
        const float* betp = bet + g*DD + ct*8;
        const float4 ga0 = *reinterpret_cast<const float4*>(gamp);
        const float4 ga1 = *reinterpret_cast<const float4*>(gamp + 4);
        const float4 bt0 = *reinterpret_cast<const float4*>(betp);
        const float4 bt1 = *reinterpret_cast<const float4*>(betp + 4);

        #pragma unroll
        for (int i = 0; i < 8; ++i) {
            const int r = rt*8 + i;
            const float4 x0 = *reinterpret_cast<const float4*>(&xg[r][ct*8]);
            const float4 x1 = *reinterpret_cast<const float4*>(&xg[r][ct*8 + 4]);
            float v0 = gelu_f(acc[i][0]) + x0.x;
            float v1 = gelu_f(acc[i][1]) + x0.y;
            float v2 = gelu_f(acc[i][2]) + x0.z;
            float v3 = gelu_f(acc[i][3]) + x0.w;
            float v4 = gelu_f(acc[i][4]) + x1.x;
            float v5 = gelu_f(acc[i][5]) + x1.y;
            float v6 = gelu_f(acc[i][6]) + x1.z;
            float v7 = gelu_f(acc[i][7]) + x1.w;

            float s = ((v0 + v1) + (v2 + v3)) + ((v4 + v5) + (v6 + v7));
            #pragma unroll
            for (int mm = 1; mm < 32; mm <<= 1) s += __shfl_xor(s, mm);
            const float mu = s * (1.0f/256.0f);

            float q = (v0-mu)*(v0-mu) + (v1-mu)*(v1-mu) + (v2-mu)*(v2-mu) + (v3-mu)*(v3-mu)
                    + (v4-mu)*(v4-mu) + (v5-mu)*(v5-mu) + (v6-mu)*(v6-mu) + (v7-mu)*(v7-mu);
            #pragma unroll
            for (int mm = 1; mm < 32; mm <<= 1) q += __shfl_xor(q, mm);
            const float sc = rsqrtf(q * (1.0f/256.0f) + EPSV);

            acc_ssr[i][0] = fmaf((v0-mu)*sc*ga0.x + bt0.x, 0.0625f, acc_ssr[i][0]);
            acc_ssr[i][1] = fmaf((v1-mu)*sc*ga0.y + bt0.y, 0.0625f, acc_ssr[i][1]);
            acc_ssr[i][2] = fmaf((v2-mu)*sc*ga0.z + bt0.z, 0.0625f, acc_ssr[i][2]);
            acc_ssr[i][3] = fmaf((v3-mu)*sc*ga0.w + bt0.w, 0.0625f, acc_ssr[i][3]);
            acc_ssr[i][4] = fmaf((v4-mu)*sc*ga1.x + bt1.x, 0.0625f, acc_ssr[i][4]);
            acc_ssr[i][5] = fmaf((v5-mu)*sc*ga1.y + bt1.y, 0.0625f, acc_ssr[i][5]);
            acc_ssr[i][6] = fmaf((v6-mu)*sc*ga1.z + bt1.z, 0.0625f, acc_ssr[i][6]);
            acc_ssr[i][7] = fmaf((v7-mu)*sc*ga1.w + bt1.w, 0.0625f, acc_ssr[i][7]);
        }
    }

    // ---- head: ssr -> relu(ssr@Wp1+bp1) -> sigmoid(@Wp2+bp2) ----
    __syncthreads();                         // all LDS reads of g-loop done
    float* ssr_s = &hb[0][0];                // reuse hb: ssr [64][256]
    float* wp1_s = &xg[0][0];                // reuse xg: Wp1 [256][64]
    #pragma unroll
    for (int i = 0; i < 8; ++i) {
        *reinterpret_cast<float4*>(&ssr_s[(rt*8 + i)*DD + ct*8]) =
            make_float4(acc_ssr[i][0], acc_ssr[i][1], acc_ssr[i][2], acc_ssr[i][3]);
        *reinterpret_cast<float4*>(&ssr_s[(rt*8 + i)*DD + ct*8 + 4]) =
            make_float4(acc_ssr[i][4], acc_ssr[i][5], acc_ssr[i][6], acc_ssr[i][7]);
    }
    {
        float4* dst = reinterpret_cast<float4*>(wp1_s);
        const float4* src = reinterpret_cast<const float4*>(Wp1);
        #pragma unroll
        for (int i = 0; i < 16; ++i) dst[t + i*256] = src[t + i*256];
    }
    __syncthreads();

    const int j  = t & 63;
    const int rr = t >> 6;                   // wave id 0..3
    const float w2j = Wp2[j];
    const float bp2v = bp2[0];
    for (int p = 0; p < 16; ++p) {
        const int r = p*4 + rr;
        float s = bp1[j];
        for (int d = 0; d < DD; ++d)
            s = fmaf(ssr_s[r*DD + d], wp1_s[d*64 + j], s);
        s = fmaxf(s, 0.f) * w2j;
        #pragma unroll
        for (int mm = 1; mm < 64; mm <<= 1) s += __shfl_xor(s, mm);
        if (j == 0) outp[b0 + r] = 1.0f / (1.0f + expf(-(s + bp2v)));
    }
}

// ---------------------------------------------------------------------------
extern "C" void kernel_launch(void* const* d_in, const int* in_sizes, int n_in,
                              void* d_out, int out_size, void* d_ws, size_t ws_size,
                              hipStream_t stream) {
    const int*   fidx  = (const int*)  d_in[0];
    const float* fval  = (const float*)d_in[1];
    const float* table = (const float*)d_in[2];
    const float* ge    = (const float*)d_in[3];
    const float* be    = (const float*)d_in[4];
    const int*   idx1  = (const int*)  d_in[5];
    const float* W1    = (const float*)d_in[6];
    const float* b1    = (const float*)d_in[7];
    const float* g1    = (const float*)d_in[8];
    const float* be1   = (const float*)d_in[9];
    const int*   idx2  = (const int*)  d_in[10];
    const float* W2    = (const float*)d_in[11];
    const float* b2    = (const float*)d_in[12];
    const float* g2    = (const float*)d_in[13];
    const float* be2   = (const float*)d_in[14];
    const float* Wp1   = (const float*)d_in[15];
    const float* bp1   = (const float*)d_in[16];
    const float* Wp2   = (const float*)d_in[17];
    const float* bp2   = (const float*)d_in[18];
    float* out = (float*)d_out;

    // workspace: xflat bf16 [B,1024] = 32MB | h1 bf16 [B,4096] = 128MB
    const size_t need = (size_t)BB*1024*2 + (size_t)BB*GD*2;
    if (ws_size < need) {
        // diagnostic path: clean fail (absmax ~0.55) instead of GPU fault
        hipMemsetAsync(d_out, 0, (size_t)out_size * sizeof(float), stream);
        return;
    }
    unsigned short* xflat = (unsigned short*)d_ws;
    unsigned short* h1    = xflat + (size_t)BB * 1024;

    embed_ln_kernel<<<BB*FF/256, 256, 0, stream>>>(fidx, fval, table, ge, be, xflat);

    dim3 gridB(BB/64, GG);
    ssr_block1_kernel<<<gridB, 256, 0, stream>>>(xflat, idx1, W1, b1, g1, be1, h1);

    ssr_block2_head_kernel<<<BB/64, 256, 0, stream>>>(h1, idx2, W2, b2, g2, be2,
                                                      Wp1, bp1, Wp2, bp2, out);
}

// Round 4
// 1021.748 us; speedup vs baseline: 3.5094x; 3.5094x over previous
//
#include <hip/hip_runtime.h>
#include <math.h>

// SSRNet constants
#define BB   16384   // batch
#define FF   64      // fields
#define EE   16      // embedding dim
#define GG   16      // groups
#define DD   256     // d_mid_cols
#define GD   4096    // GG*DD
#define EPSV 1e-3f

typedef unsigned short u16;
typedef __attribute__((ext_vector_type(8))) short bf16x8;   // 8 bf16 = 4 VGPR
typedef __attribute__((ext_vector_type(4))) float f32x4;    // MFMA acc
#define MFMA16(a,b,c) __builtin_amdgcn_mfma_f32_16x16x32_bf16(a,b,c,0,0,0)

__device__ __forceinline__ float gelu_f(float x) {
    return 0.5f * x * (1.0f + erff(x * 0.70710678118654752f));
}
__device__ __forceinline__ u16 f2bf(float f) {
    unsigned x = __float_as_uint(f);
    return (u16)((x + 0x7fffu + ((x >> 16) & 1u)) >> 16);
}
__device__ __forceinline__ float bf2f(u16 u) {
    return __uint_as_float(((unsigned)u) << 16);
}
__device__ __forceinline__ unsigned pk2(float a, float b) {
    return (unsigned)f2bf(a) | ((unsigned)f2bf(b) << 16);
}

// ---------------------------------------------------------------------------
// Kernel 0: prepack W1,W2 (fp32 [g][l][d][n]) -> bf16 MFMA-B-fragment layout:
// wpack frag idx = ((gl*8 + kt)*16 + nt)*64 + lane, 8 bf16 per frag.
// gl = g*2+l for W1 (0..31), 32+g*2+l for W2 (32..63).
// B[k][n]: lane holds n = lane&15, k = kt*32 + (lane>>4)*8 + e.
// ---------------------------------------------------------------------------
__global__ __launch_bounds__(256)
void prepack_kernel(const float* __restrict__ W1, const float* __restrict__ W2,
                    u16* __restrict__ wpack) {
    const int tid  = blockIdx.x * 256 + threadIdx.x;   // 0..524287 exact
    const int lane = tid & 63;
    int rest = tid >> 6;
    const int nt = rest & 15; rest >>= 4;
    const int kt = rest & 7;
    const int gl = rest >> 3;                          // 0..63
    const float* src = (gl < 32) ? (W1 + (size_t)gl * 65536)
                                 : (W2 + (size_t)(gl - 32) * 65536);
    const int d0 = kt*32 + (lane >> 4) * 8;
    const int n  = nt*16 + (lane & 15);
    u16 o[8];
    #pragma unroll
    for (int e = 0; e < 8; ++e)
        o[e] = f2bf(src[(size_t)(d0 + e) * 256 + n]);
    uint4 pk;
    pk.x = (unsigned)o[0] | ((unsigned)o[1] << 16);
    pk.y = (unsigned)o[2] | ((unsigned)o[3] << 16);
    pk.z = (unsigned)o[4] | ((unsigned)o[5] << 16);
    pk.w = (unsigned)o[6] | ((unsigned)o[7] << 16);
    reinterpret_cast<uint4*>(wpack)[tid] = pk;
}

// ---------------------------------------------------------------------------
// Kernel 1: emb = table[feat_index]*feat_value ; LN over E=16 -> bf16 xflat
// ---------------------------------------------------------------------------
__global__ __launch_bounds__(256)
void embed_ln_kernel(const int* __restrict__ fidx,
                     const float* __restrict__ fval,
                     const float* __restrict__ table,
                     const float* __restrict__ gamma,
                     const float* __restrict__ beta,
                     u16* __restrict__ xflat) {
    const int t = blockIdx.x * blockDim.x + threadIdx.x;
    const int row = fidx[t];
    const float v = fval[t];
    const float4* src = reinterpret_cast<const float4*>(table) + (size_t)row * 4;
    float4 e0 = src[0], e1 = src[1], e2 = src[2], e3 = src[3];
    float x[16] = {e0.x,e0.y,e0.z,e0.w, e1.x,e1.y,e1.z,e1.w,
                   e2.x,e2.y,e2.z,e2.w, e3.x,e3.y,e3.z,e3.w};
    float s = 0.f;
    #pragma unroll
    for (int j = 0; j < 16; ++j) { x[j] *= v; s += x[j]; }
    const float mu = s * (1.0f/16.0f);
    float q = 0.f;
    #pragma unroll
    for (int j = 0; j < 16; ++j) { float d = x[j] - mu; q += d*d; }
    const float sc = rsqrtf(q * (1.0f/16.0f) + EPSV);
    float o[16];
    #pragma unroll
    for (int j = 0; j < 16; ++j) o[j] = (x[j] - mu) * sc * gamma[j] + beta[j];
    uint4 p0, p1;
    p0.x = pk2(o[0], o[1]);   p0.y = pk2(o[2], o[3]);
    p0.z = pk2(o[4], o[5]);   p0.w = pk2(o[6], o[7]);
    p1.x = pk2(o[8], o[9]);   p1.y = pk2(o[10], o[11]);
    p1.z = pk2(o[12], o[13]); p1.w = pk2(o[14], o[15]);
    uint4* dst = reinterpret_cast<uint4*>(xflat) + (size_t)t * 2;
    dst[0] = p0;
    dst[1] = p1;
}

// ---------------------------------------------------------------------------
// Kernel 2: SSR block 1, MFMA. grid 4096 (XCD-swizzled (tile,g)), 256 thr.
// LDS 64KB (xg,hb bf16 [64][256] XOR-swizzled) -> 2 blocks/CU.
// Waves col-split: wave wv owns cols wv*64..+64; rows all 64.
// ---------------------------------------------------------------------------
__global__ __launch_bounds__(256, 2)
void ssr1_mfma(const u16* __restrict__ xin,     // [B,1024] bf16
               const int* __restrict__ idx,     // [G,256]
               const u16* __restrict__ wpack,
               const float* __restrict__ bias,  // [G,2,256]
               const float* __restrict__ gam,
               const float* __restrict__ bet,
               u16* __restrict__ h1) {          // [B,4096] bf16
    __shared__ char sm[65536];
    char* xg = sm;            // bf16 [64][256] swizzled: byte ^= (row&7)<<4
    char* hb = sm + 32768;

    const int bx = blockIdx.x;
    const int g    = ((bx & 7) << 1) | ((bx >> 3) & 1);  // XCD-local group pair
    const int tile = bx >> 4;
    const int b0 = tile * 64;
    const int t = threadIdx.x, lane = t & 63, wv = t >> 6;
    const int ln15 = lane & 15, lhi = lane >> 4;

    // gather: xg[r][t] = xin[b0+r][idx1[g][t]]
    {
        const int col = idx[g*256 + t];
        const u16* src = xin + (size_t)b0 * 1024 + col;
        #pragma unroll 4
        for (int r = 0; r < 64; ++r) {
            const int byte = (r*512 + t*2) ^ ((r & 7) << 4);
            *reinterpret_cast<u16*>(xg + byte) = src[(size_t)r * 1024];
        }
    }
    __syncthreads();

    f32x4 acc[4][4];
    for (int l = 0; l < 2; ++l) {
        const char* A = l ? hb : xg;
        const bf16x8* bp = reinterpret_cast<const bf16x8*>(wpack)
                         + ((size_t)(g*2 + l) * 128 + wv*4) * 64 + lane;
        const float* bg = bias + (g*2 + l) * 256;
        #pragma unroll
        for (int nl = 0; nl < 4; ++nl) {
            const float bv = bg[(wv*4 + nl)*16 + ln15];
            #pragma unroll
            for (int rt = 0; rt < 4; ++rt) acc[rt][nl] = (f32x4){bv, bv, bv, bv};
        }
        bf16x8 bcur[4];
        #pragma unroll
        for (int nl = 0; nl < 4; ++nl) bcur[nl] = bp[nl*64];
        for (int kt = 0; kt < 8; ++kt) {
            bf16x8 bnext[4];
            if (kt < 7) {
                #pragma unroll
                for (int nl = 0; nl < 4; ++nl) bnext[nl] = bp[(kt+1)*1024 + nl*64];
            }
            bf16x8 afr[4];
            #pragma unroll
            for (int rt = 0; rt < 4; ++rt) {
                const int row = rt*16 + ln15;
                const int byte = (row*512 + kt*64 + lhi*16) ^ ((row & 7) << 4);
                afr[rt] = *reinterpret_cast<const bf16x8*>(A + byte);
            }
            #pragma unroll
            for (int rt = 0; rt < 4; ++rt)
                #pragma unroll
                for (int nl = 0; nl < 4; ++nl)
                    acc[rt][nl] = MFMA16(afr[rt], bcur[nl], acc[rt][nl]);
            #pragma unroll
            for (int nl = 0; nl < 4; ++nl) bcur[nl] = bnext[nl];
        }
        if (l == 0) {
            // gelu -> hb (no barrier needed before: hb unread in l=0)
            #pragma unroll
            for (int rt = 0; rt < 4; ++rt)
                #pragma unroll
                for (int nl = 0; nl < 4; ++nl)
                    #pragma unroll
                    for (int q = 0; q < 4; ++q) {
                        const int row = rt*16 + lhi*4 + q;
                        const int cn  = (wv*4 + nl)*16 + ln15;
                        const int byte = (row*512 + cn*2) ^ ((row & 7) << 4);
                        *reinterpret_cast<u16*>(hb + byte) = f2bf(gelu_f(acc[rt][nl][q]));
                    }
            __syncthreads();
        }
    }

    // v = gelu(acc) + x -> hb (bf16), after all l=1 hb reads complete
    __syncthreads();
    #pragma unroll
    for (int rt = 0; rt < 4; ++rt)
        #pragma unroll
        for (int nl = 0; nl < 4; ++nl)
            #pragma unroll
            for (int q = 0; q < 4; ++q) {
                const int row = rt*16 + lhi*4 + q;
                const int cn  = (wv*4 + nl)*16 + ln15;
                const int byte = (row*512 + cn*2) ^ ((row & 7) << 4);
                const float x = bf2f(*reinterpret_cast<const u16*>(xg + byte));
                *reinterpret_cast<u16*>(hb + byte) = f2bf(gelu_f(acc[rt][nl][q]) + x);
            }
    __syncthreads();

    // LN: thread -> row = t>>2, quarter q4 = t&3 (cols q4*64..+64)
    {
        const int row = t >> 2, q4 = t & 3;
        const int rswz = (row & 7) << 4;
        uint4 raw[8];
        #pragma unroll
        for (int i = 0; i < 8; ++i)
            raw[i] = *reinterpret_cast<const uint4*>(hb + ((row*512 + q4*128 + i*16) ^ rswz));
        float v[64];
        float s = 0.f;
        #pragma unroll
        for (int i = 0; i < 8; ++i) {
            const unsigned u[4] = {raw[i].x, raw[i].y, raw[i].z, raw[i].w};
            #pragma unroll
            for (int w = 0; w < 4; ++w) {
                const float a = bf2f((u16)(u[w] & 0xffffu));
                const float b = bf2f((u16)(u[w] >> 16));
                v[i*8 + w*2]     = a;
                v[i*8 + w*2 + 1] = b;
                s += a + b;
            }
        }
        s += __shfl_xor(s, 1); s += __shfl_xor(s, 2);
        const float mu = s * (1.0f/256.0f);
        float ss = 0.f;
        #pragma unroll
        for (int j = 0; j < 64; ++j) { const float d = v[j] - mu; ss += d*d; }
        ss += __shfl_xor(ss, 1); ss += __shfl_xor(ss, 2);
        const float sc = rsqrtf(ss * (1.0f/256.0f) + EPSV);

        const float4* gap = reinterpret_cast<const float4*>(gam + g*256 + q4*64);
        const float4* btp = reinterpret_cast<const float4*>(bet + g*256 + q4*64);
        u16* dst = h1 + (size_t)(b0 + row) * 4096 + g*256 + q4*64;
        #pragma unroll
        for (int i = 0; i < 8; ++i) {
            const float4 ga0 = gap[i*2], ga1 = gap[i*2+1];
            const float4 bt0 = btp[i*2], bt1 = btp[i*2+1];
            const float gaa[8] = {ga0.x,ga0.y,ga0.z,ga0.w, ga1.x,ga1.y,ga1.z,ga1.w};
            const float bta[8] = {bt0.x,bt0.y,bt0.z,bt0.w, bt1.x,bt1.y,bt1.z,bt1.w};
            float o[8];
            #pragma unroll
            for (int w = 0; w < 8; ++w) o[w] = (v[i*8 + w] - mu) * sc * gaa[w] + bta[w];
            uint4 pk;
            pk.x = pk2(o[0], o[1]); pk.y = pk2(o[2], o[3]);
            pk.z = pk2(o[4], o[5]); pk.w = pk2(o[6], o[7]);
            reinterpret_cast<uint4*>(dst)[i] = pk;
        }
    }
}

// ---------------------------------------------------------------------------
// Kernel 3: SSR block 2 + group-mean + head, MFMA. grid 256, 512 thr (8 waves).
// Waves col-split (2 coltiles each). ssr accumulated in registers per
// (row=t>>3, cols (t&7)*32..+32); head via LDS at the end.
// ---------------------------------------------------------------------------
__global__ __launch_bounds__(512, 1)
void ssr2_head_mfma(const u16* __restrict__ h1,   // [B,4096] bf16
                    const int* __restrict__ idx,  // [G,256]
                    const u16* __restrict__ wpack,
                    const float* __restrict__ bias,
                    const float* __restrict__ gam,
                    const float* __restrict__ bet,
                    const float* __restrict__ Wp1, // [256,64]
                    const float* __restrict__ bp1, // [64]
                    const float* __restrict__ Wp2, // [64]
                    const float* __restrict__ bp2, // [1]
                    float* __restrict__ outp) {    // [B]
    __shared__ char sm[65536];           // xg | hb (bf16 [64][256] swizzled)
    __shared__ float ssr_s[64*8*33];     // [row][oct][33] padded
    char* xg = sm;
    char* hb = sm + 32768;

    const int b0 = blockIdx.x * 64;
    const int t = threadIdx.x, lane = t & 63, wv = t >> 6;
    const int ln15 = lane & 15, lhi = lane >> 4;
    const int grow = t >> 3, goct = t & 7;    // LN/ssr mapping
    const int gc = t & 255, ghalf = t >> 8;   // gather mapping

    float accs[32];
    #pragma unroll
    for (int j = 0; j < 32; ++j) accs[j] = 0.f;

    for (int g = 0; g < GG; ++g) {
        // gather: xg[r][gc] = h1[b0+r][idx2[g][gc]]
        {
            const int col = idx[g*256 + gc];
            const u16* src = h1 + (size_t)(b0 + ghalf*32) * 4096 + col;
            #pragma unroll 4
            for (int r = 0; r < 32; ++r) {
                const int row = ghalf*32 + r;
                const int byte = (row*512 + gc*2) ^ ((row & 7) << 4);
                *reinterpret_cast<u16*>(xg + byte) = src[(size_t)r * 4096];
            }
        }
        __syncthreads();

        f32x4 acc[4][2];
        for (int l = 0; l < 2; ++l) {
            const char* A = l ? hb : xg;
            const bf16x8* bp = reinterpret_cast<const bf16x8*>(wpack)
                             + ((size_t)(32 + g*2 + l) * 128 + wv*2) * 64 + lane;
            const float* bg = bias + (g*2 + l) * 256;
            #pragma unroll
            for (int nl = 0; nl < 2; ++nl) {
                const float bv = bg[(wv*2 + nl)*16 + ln15];
                #pragma unroll
                for (int rt = 0; rt < 4; ++rt) acc[rt][nl] = (f32x4){bv, bv, bv, bv};
            }
            bf16x8 bcur[2];
            bcur[0] = bp[0]; bcur[1] = bp[64];
            for (int kt = 0; kt < 8; ++kt) {
                bf16x8 bnext[2];
                if (kt < 7) { bnext[0] = bp[(kt+1)*1024]; bnext[1] = bp[(kt+1)*1024 + 64]; }
                bf16x8 afr[4];
                #pragma unroll
                for (int rt = 0; rt < 4; ++rt) {
                    const int row = rt*16 + ln15;
                    const int byte = (row*512 + kt*64 + lhi*16) ^ ((row & 7) << 4);
                    afr[rt] = *reinterpret_cast<const bf16x8*>(A + byte);
                }
                #pragma unroll
                for (int rt = 0; rt < 4; ++rt) {
                    acc[rt][0] = MFMA16(afr[rt], bcur[0], acc[rt][0]);
                    acc[rt][1] = MFMA16(afr[rt], bcur[1], acc[rt][1]);
                }
                bcur[0] = bnext[0]; bcur[1] = bnext[1];
            }
            if (l == 0) {
                #pragma unroll
                for (int rt = 0; rt < 4; ++rt)
                    #pragma unroll
                    for (int nl = 0; nl < 2; ++nl)
                        #pragma unroll
                        for (int q = 0; q < 4; ++q) {
                            const int row = rt*16 + lhi*4 + q;
                            const int cn  = (wv*2 + nl)*16 + ln15;
                            const int byte = (row*512 + cn*2) ^ ((row & 7) << 4);
                            *reinterpret_cast<u16*>(hb + byte) = f2bf(gelu_f(acc[rt][nl][q]));
                        }
                __syncthreads();
            }
        }
        __syncthreads();   // l=1 hb reads done
        #pragma unroll
        for (int rt = 0; rt < 4; ++rt)
            #pragma unroll
            for (int nl = 0; nl < 2; ++nl)
                #pragma unroll
                for (int q = 0; q < 4; ++q) {
                    const int row = rt*16 + lhi*4 + q;
                    const int cn  = (wv*2 + nl)*16 + ln15;
                    const int byte = (row*512 + cn*2) ^ ((row & 7) << 4);
                    const float x = bf2f(*reinterpret_cast<const u16*>(xg + byte));
                    *reinterpret_cast<u16*>(hb + byte) = f2bf(gelu_f(acc[rt][nl][q]) + x);
                }
        __syncthreads();

        // LN + ssr accumulate: row = grow, cols goct*32..+32
        {
            const int rswz = (grow & 7) << 4;
            uint4 raw[4];
            #pragma unroll
            for (int i = 0; i < 4; ++i)
                raw[i] = *reinterpret_cast<const uint4*>(hb + ((grow*512 + goct*64 + i*16) ^ rswz));
            float v[32];
            float s = 0.f;
            #pragma unroll
            for (int i = 0; i < 4; ++i) {
                const unsigned u[4] = {raw[i].x, raw[i].y, raw[i].z, raw[i].w};
                #pragma unroll
                for (int w = 0; w < 4; ++w) {
                    const float a = bf2f((u16)(u[w] & 0xffffu));
                    const float b = bf2f((u16)(u[w] >> 16));
                    v[i*8 + w*2]     = a;
                    v[i*8 + w*2 + 1] = b;
                    s += a + b;
                }
            }
            s += __shfl_xor(s, 1); s += __shfl_xor(s, 2); s += __shfl_xor(s, 4);
            const float mu = s * (1.0f/256.0f);
            float ss = 0.f;
            #pragma unroll
            for (int j = 0; j < 32; ++j) { const float d = v[j] - mu; ss += d*d; }
            ss += __shfl_xor(ss, 1); ss += __shfl_xor(ss, 2); ss += __shfl_xor(ss, 4);
            const float sc = rsqrtf(ss * (1.0f/256.0f) + EPSV);
            const float4* gap = reinterpret_cast<const float4*>(gam + g*256 + goct*32);
            const float4* btp = reinterpret_cast<const float4*>(bet + g*256 + goct*32);
            #pragma unroll
            for (int i = 0; i < 8; ++i) {
                const float4 ga = gap[i], bt = btp[i];
                const float gaa[4] = {ga.x, ga.y, ga.z, ga.w};
                const float bta[4] = {bt.x, bt.y, bt.z, bt.w};
                #pragma unroll
                for (int w = 0; w < 4; ++w)
                    accs[i*4 + w] = fmaf((v[i*4 + w] - mu) * sc * gaa[w] + bta[w],
                                         0.0625f, accs[i*4 + w]);
            }
        }
        __syncthreads();   // before next gather overwrites xg (and l=0 hb)
    }

    // ---- head ----
    #pragma unroll
    for (int j = 0; j < 32; ++j)
        ssr_s[grow*264 + goct*33 + j] = accs[j];
    float* wp1_s = reinterpret_cast<float*>(sm);   // 64KB: Wp1 [256][64] fp32
    #pragma unroll
    for (int i = 0; i < 32; ++i)
        wp1_s[t + i*512] = Wp1[t + i*512];
    __syncthreads();
    {
        const int j = t & 63, rq = t >> 6;
        const float w2j = Wp2[j], b1j = bp1[j], b2v = bp2[0];
        #pragma unroll
        for (int k = 0; k < 8; ++k) {
            const int row = k*8 + rq;
            const float* sr = ssr_s + row*264;
            float s = b1j;
            #pragma unroll 8
            for (int d = 0; d < 256; ++d)
                s = fmaf(sr[(d >> 5)*33 + (d & 31)], wp1_s[d*64 + j], s);
            s = fmaxf(s, 0.f) * w2j;
            #pragma unroll
            for (int mm = 1; mm < 64; mm <<= 1) s += __shfl_xor(s, mm);
            if (j == 0) outp[b0 + row] = 1.0f / (1.0f + expf(-(s + b2v)));
        }
    }
}

// ---------------------------------------------------------------------------
extern "C" void kernel_launch(void* const* d_in, const int* in_sizes, int n_in,
                              void* d_out, int out_size, void* d_ws, size_t ws_size,
                              hipStream_t stream) {
    const int*   fidx  = (const int*)  d_in[0];
    const float* fval  = (const float*)d_in[1];
    const float* table = (const float*)d_in[2];
    const float* ge    = (const float*)d_in[3];
    const float* be    = (const float*)d_in[4];
    const int*   idx1  = (const int*)  d_in[5];
    const float* W1    = (const float*)d_in[6];
    const float* b1    = (const float*)d_in[7];
    const float* g1    = (const float*)d_in[8];
    const float* be1   = (const float*)d_in[9];
    const int*   idx2  = (const int*)  d_in[10];
    const float* W2    = (const float*)d_in[11];
    const float* b2    = (const float*)d_in[12];
    const float* g2    = (const float*)d_in[13];
    const float* be2   = (const float*)d_in[14];
    const float* Wp1   = (const float*)d_in[15];
    const float* bp1   = (const float*)d_in[16];
    const float* Wp2   = (const float*)d_in[17];
    const float* bp2   = (const float*)d_in[18];
    float* out = (float*)d_out;

    // ws: wpack bf16 8.39MB | xflat bf16 32MB | h1 bf16 128MB  (~168MB)
    const size_t wpack_elems = (size_t)64 * 8 * 16 * 64 * 8;   // 4,194,304
    const size_t need = wpack_elems*2 + (size_t)BB*1024*2 + (size_t)BB*GD*2;
    if (ws_size < need) {
        hipMemsetAsync(d_out, 0, (size_t)out_size * sizeof(float), stream);
        return;
    }
    u16* wpack = (u16*)d_ws;
    u16* xflat = wpack + wpack_elems;
    u16* h1    = xflat + (size_t)BB * 1024;

    prepack_kernel<<<2048, 256, 0, stream>>>(W1, W2, wpack);
    embed_ln_kernel<<<BB*FF/256, 256, 0, stream>>>(fidx, fval, table, ge, be, xflat);
    ssr1_mfma<<<4096, 256, 0, stream>>>(xflat, idx1, wpack, b1, g1, be1, h1);
    ssr2_head_mfma<<<BB/64, 512, 0, stream>>>(h1, idx2, wpack, b2, g2, be2,
                                              Wp1, bp1, Wp2, bp2, out);
}

// Round 5
// 956.601 us; speedup vs baseline: 3.7484x; 1.0681x over previous
//
#include <hip/hip_runtime.h>
#include <math.h>

// SSRNet constants
#define BB   16384   // batch
#define FF   64      // fields
#define EE   16      // embedding dim
#define GG   16      // groups
#define DD   256     // d_mid_cols
#define GD   4096    // GG*DD
#define EPSV 1e-3f

typedef unsigned short u16;
typedef __attribute__((ext_vector_type(8))) short bf16x8;   // 8 bf16 = 4 VGPR
typedef __attribute__((ext_vector_type(4))) float f32x4;    // MFMA acc
#define MFMA16(a,b,c) __builtin_amdgcn_mfma_f32_16x16x32_bf16(a,b,c,0,0,0)

__device__ __forceinline__ float gelu_f(float x) {
    return 0.5f * x * (1.0f + erff(x * 0.70710678118654752f));
}
__device__ __forceinline__ u16 f2bf(float f) {
    unsigned x = __float_as_uint(f);
    return (u16)((x + 0x7fffu + ((x >> 16) & 1u)) >> 16);
}
__device__ __forceinline__ float bf2f(u16 u) {
    return __uint_as_float(((unsigned)u) << 16);
}
__device__ __forceinline__ unsigned pk2(float a, float b) {
    return (unsigned)f2bf(a) | ((unsigned)f2bf(b) << 16);
}

// ---------------------------------------------------------------------------
// Kernel 0: prepack W1,W2 -> bf16 MFMA-B-fragment layout (unchanged from R4).
// frag idx = ((gl*8 + kt)*16 + nt)*64 + lane; B[k][n]: n=lane&15,
// k = kt*32 + (lane>>4)*8 + e. gl: W1 -> g*2+l, W2 -> 32+g*2+l.
// ---------------------------------------------------------------------------
__global__ __launch_bounds__(256)
void prepack_kernel(const float* __restrict__ W1, const float* __restrict__ W2,
                    u16* __restrict__ wpack) {
    const int tid  = blockIdx.x * 256 + threadIdx.x;
    const int lane = tid & 63;
    int rest = tid >> 6;
    const int nt = rest & 15; rest >>= 4;
    const int kt = rest & 7;
    const int gl = rest >> 3;
    const float* src = (gl < 32) ? (W1 + (size_t)gl * 65536)
                                 : (W2 + (size_t)(gl - 32) * 65536);
    const int d0 = kt*32 + (lane >> 4) * 8;
    const int n  = nt*16 + (lane & 15);
    u16 o[8];
    #pragma unroll
    for (int e = 0; e < 8; ++e)
        o[e] = f2bf(src[(size_t)(d0 + e) * 256 + n]);
    uint4 pk;
    pk.x = (unsigned)o[0] | ((unsigned)o[1] << 16);
    pk.y = (unsigned)o[2] | ((unsigned)o[3] << 16);
    pk.z = (unsigned)o[4] | ((unsigned)o[5] << 16);
    pk.w = (unsigned)o[6] | ((unsigned)o[7] << 16);
    reinterpret_cast<uint4*>(wpack)[tid] = pk;
}

// ---------------------------------------------------------------------------
// Kernel 1: embed + LN(E=16) -> xflatT [1024 feat][16384 b] bf16 (TRANSPOSED)
// block = 64 b x 16 f (256 feats); LDS transpose then 16B coalesced stores.
// ---------------------------------------------------------------------------
__global__ __launch_bounds__(256)
void embed_ln_kernel(const int* __restrict__ fidx,
                     const float* __restrict__ fval,
                     const float* __restrict__ table,
                     const float* __restrict__ gamma,
                     const float* __restrict__ beta,
                     u16* __restrict__ xT) {
    __shared__ u16 lt[256 * 64];   // [feat_local 256][b_local 64] = 32KB
    const int bx = blockIdx.x;
    const int bslab = bx >> 2, fslab = bx & 3;
    const int b0 = bslab * 64;
    const int t = threadIdx.x;
    #pragma unroll
    for (int i = 0; i < 4; ++i) {
        const int c = t + i*256;           // 0..1023
        const int b = c & 63, f = c >> 6;  // f 0..15
        const int gi = (b0 + b)*FF + fslab*16 + f;
        const int row = fidx[gi];
        const float v = fval[gi];
        const float4* src = reinterpret_cast<const float4*>(table) + (size_t)row * 4;
        float4 e0 = src[0], e1 = src[1], e2 = src[2], e3 = src[3];
        float x[16] = {e0.x,e0.y,e0.z,e0.w, e1.x,e1.y,e1.z,e1.w,
                       e2.x,e2.y,e2.z,e2.w, e3.x,e3.y,e3.z,e3.w};
        float s = 0.f;
        #pragma unroll
        for (int j = 0; j < 16; ++j) { x[j] *= v; s += x[j]; }
        const float mu = s * (1.0f/16.0f);
        float q = 0.f;
        #pragma unroll
        for (int j = 0; j < 16; ++j) { float d = x[j] - mu; q += d*d; }
        const float sc = rsqrtf(q * (1.0f/16.0f) + EPSV);
        #pragma unroll
        for (int e = 0; e < 16; ++e)
            lt[(f*16 + e)*64 + b] = f2bf((x[e] - mu) * sc * gamma[e] + beta[e]);
    }
    __syncthreads();
    #pragma unroll
    for (int i = 0; i < 8; ++i) {
        const int u = t + i*256;           // uint4 id 0..2047
        const int feat = u >> 3, bq = u & 7;
        reinterpret_cast<uint4*>(xT + (size_t)(fslab*256 + feat)*BB + b0)[bq] =
            reinterpret_cast<const uint4*>(lt)[u];
    }
}

// ---------------------------------------------------------------------------
// Kernel 2: SSR block 1, MFMA. grid 4096 = (tile, g XCD-mapped), 256 thr.
// In: xflatT (coalesced row gather); out: h1T [4096][16384] bf16.
// LDS: xg 32KB + hb 32KB (+musc) -> 2 blocks/CU.
// ---------------------------------------------------------------------------
__global__ __launch_bounds__(256, 2)
void ssr1_mfma(const u16* __restrict__ xT,      // [1024][BB]
               const int* __restrict__ idx,     // [G,256]
               const u16* __restrict__ wpack,
               const float* __restrict__ bias,  // [G,2,256]
               const float* __restrict__ gam,
               const float* __restrict__ bet,
               u16* __restrict__ h1T) {         // [4096][BB]
    __shared__ char sm[65536];
    __shared__ float musc[64][2];
    char* xg = sm;            // bf16 [64][256] swizzled: byte ^= (row&7)<<4
    char* hb = sm + 32768;

    const int bx = blockIdx.x;
    const int g  = ((bx & 7) << 1) | ((bx >> 3) & 1);
    const int b0 = (bx >> 4) * 64;
    const int t = threadIdx.x, lane = t & 63, wv = t >> 6;
    const int ln15 = lane & 15, lhi = lane >> 4;

    // gather: coalesced 128B row read from xT, LDS-transpose into xg[r][t]
    {
        const int col = idx[g*256 + t];
        const uint4* src = reinterpret_cast<const uint4*>(xT + (size_t)col*BB + b0);
        uint4 nx[8];
        #pragma unroll
        for (int j = 0; j < 8; ++j) nx[j] = src[j];
        #pragma unroll
        for (int j = 0; j < 8; ++j) {
            const unsigned uu[4] = {nx[j].x, nx[j].y, nx[j].z, nx[j].w};
            #pragma unroll
            for (int k = 0; k < 8; ++k) {
                const int r = j*8 + k;
                const int byte = (r*512 + t*2) ^ ((r & 7) << 4);
                *reinterpret_cast<u16*>(xg + byte) =
                    (k & 1) ? (u16)(uu[k >> 1] >> 16) : (u16)(uu[k >> 1] & 0xffffu);
            }
        }
    }
    __syncthreads();

    f32x4 acc[4][4];
    for (int l = 0; l < 2; ++l) {
        const char* A = l ? hb : xg;
        const bf16x8* bp = reinterpret_cast<const bf16x8*>(wpack)
                         + ((size_t)(g*2 + l) * 128 + wv*4) * 64 + lane;
        const float* bg = bias + (g*2 + l) * 256;
        #pragma unroll
        for (int nl = 0; nl < 4; ++nl) {
            const float bv = bg[(wv*4 + nl)*16 + ln15];
            #pragma unroll
            for (int rt = 0; rt < 4; ++rt) acc[rt][nl] = (f32x4){bv, bv, bv, bv};
        }
        bf16x8 bcur[4];
        #pragma unroll
        for (int nl = 0; nl < 4; ++nl) bcur[nl] = bp[nl*64];
        for (int kt = 0; kt < 8; ++kt) {
            bf16x8 bnext[4];
            if (kt < 7) {
                #pragma unroll
                for (int nl = 0; nl < 4; ++nl) bnext[nl] = bp[(kt+1)*1024 + nl*64];
            }
            bf16x8 afr[4];
            #pragma unroll
            for (int rt = 0; rt < 4; ++rt) {
                const int row = rt*16 + ln15;
                const int byte = (row*512 + kt*64 + lhi*16) ^ ((row & 7) << 4);
                afr[rt] = *reinterpret_cast<const bf16x8*>(A + byte);
            }
            #pragma unroll
            for (int rt = 0; rt < 4; ++rt)
                #pragma unroll
                for (int nl = 0; nl < 4; ++nl)
                    acc[rt][nl] = MFMA16(afr[rt], bcur[nl], acc[rt][nl]);
            #pragma unroll
            for (int nl = 0; nl < 4; ++nl) bcur[nl] = bnext[nl];
        }
        if (l == 0) {
            #pragma unroll
            for (int rt = 0; rt < 4; ++rt)
                #pragma unroll
                for (int nl = 0; nl < 4; ++nl)
                    #pragma unroll
                    for (int q = 0; q < 4; ++q) {
                        const int row = rt*16 + lhi*4 + q;
                        const int cn  = (wv*4 + nl)*16 + ln15;
                        const int byte = (row*512 + cn*2) ^ ((row & 7) << 4);
                        *reinterpret_cast<u16*>(hb + byte) = f2bf(gelu_f(acc[rt][nl][q]));
                    }
            __syncthreads();
        }
    }

    // v = gelu(acc) + x -> hb (bf16) after l=1 hb frag reads complete
    __syncthreads();
    #pragma unroll
    for (int rt = 0; rt < 4; ++rt)
        #pragma unroll
        for (int nl = 0; nl < 4; ++nl)
            #pragma unroll
            for (int q = 0; q < 4; ++q) {
                const int row = rt*16 + lhi*4 + q;
                const int cn  = (wv*4 + nl)*16 + ln15;
                const int byte = (row*512 + cn*2) ^ ((row & 7) << 4);
                const float x = bf2f(*reinterpret_cast<const u16*>(xg + byte));
                *reinterpret_cast<u16*>(hb + byte) = f2bf(gelu_f(acc[rt][nl][q]) + x);
            }
    __syncthreads();

    // LN stats: row = t>>2, quarter q4 = t&3; publish mu/sc to musc
    {
        const int row = t >> 2, q4 = t & 3;
        const int rswz = (row & 7) << 4;
        uint4 raw[8];
        #pragma unroll
        for (int i = 0; i < 8; ++i)
            raw[i] = *reinterpret_cast<const uint4*>(hb + ((row*512 + q4*128 + i*16) ^ rswz));
        float v[64];
        float s = 0.f;
        #pragma unroll
        for (int i = 0; i < 8; ++i) {
            const unsigned u[4] = {raw[i].x, raw[i].y, raw[i].z, raw[i].w};
            #pragma unroll
            for (int w = 0; w < 4; ++w) {
                const float a = bf2f((u16)(u[w] & 0xffffu));
                const float b = bf2f((u16)(u[w] >> 16));
                v[i*8 + w*2]     = a;
                v[i*8 + w*2 + 1] = b;
                s += a + b;
            }
        }
        s += __shfl_xor(s, 1); s += __shfl_xor(s, 2);
        const float mu = s * (1.0f/256.0f);
        float ss = 0.f;
        #pragma unroll
        for (int j = 0; j < 64; ++j) { const float d = v[j] - mu; ss += d*d; }
        ss += __shfl_xor(ss, 1); ss += __shfl_xor(ss, 2);
        const float sc = rsqrtf(ss * (1.0f/256.0f) + EPSV);
        if (q4 == 0) { musc[row][0] = mu; musc[row][1] = sc; }
    }
    __syncthreads();

    // transposed writer: thread t = feature cn; read hb column, write 128B row
    {
        const int cn = t;
        const float ga  = gam[g*256 + cn];
        const float bt_ = bet[g*256 + cn];
        unsigned wds[32];
        #pragma unroll
        for (int rp = 0; rp < 32; ++rp) {
            float o[2];
            #pragma unroll
            for (int h = 0; h < 2; ++h) {
                const int r = rp*2 + h;
                const u16 vv = *reinterpret_cast<const u16*>(
                    hb + ((r*512 + cn*2) ^ ((r & 7) << 4)));
                o[h] = (bf2f(vv) - musc[r][0]) * musc[r][1] * ga + bt_;
            }
            wds[rp] = pk2(o[0], o[1]);
        }
        uint4* dst = reinterpret_cast<uint4*>(h1T + (size_t)(g*256 + cn)*BB + b0);
        #pragma unroll
        for (int q = 0; q < 8; ++q)
            dst[q] = make_uint4(wds[q*4], wds[q*4+1], wds[q*4+2], wds[q*4+3]);
    }
}

// ---------------------------------------------------------------------------
// Kernel 3: SSR block 2 (8 groups per block) -> partial ssr. grid 512
// (tile = bx&255, gset = bx>>8), 512 thr, LDS 64KB -> 2 blocks/CU.
// Coalesced gather from h1T with T14 prefetch of next group.
// ---------------------------------------------------------------------------
__global__ __launch_bounds__(512, 4)
void ssr2_mfma(const u16* __restrict__ h1T,   // [4096][BB]
               const int* __restrict__ idx,   // [G,256]
               const u16* __restrict__ wpack,
               const float* __restrict__ bias,
               const float* __restrict__ gam,
               const float* __restrict__ bet,
               float* __restrict__ pssr) {    // [2][BB][256] f32
    __shared__ char sm[65536];
    char* xg = sm;
    char* hb = sm + 32768;

    const int bx = blockIdx.x;
    const int tile = bx & 255, gset = bx >> 8;
    const int b0 = tile * 64;
    const int t = threadIdx.x, lane = t & 63, wv = t >> 6;
    const int ln15 = lane & 15, lhi = lane >> 4;
    const int gd = t >> 1, grh = t & 1;       // gather: feature, r-half
    const int grow = t >> 3, goct = t & 7;    // LN/ssr mapping

    float accs[32];
    #pragma unroll
    for (int j = 0; j < 32; ++j) accs[j] = 0.f;

    uint4 nx[4];
    {   // prologue: load group gset*8
        const int col = idx[(gset*8)*256 + gd];
        const uint4* src = reinterpret_cast<const uint4*>(h1T + (size_t)col*BB + b0 + grh*32);
        #pragma unroll
        for (int j = 0; j < 4; ++j) nx[j] = src[j];
    }

    for (int gi = 0; gi < 8; ++gi) {
        const int g = gset*8 + gi;
        __syncthreads();   // xg/hb free (prev LN done)
        // LDS-transpose write of gathered rows (uses nx -> implicit vmcnt wait)
        #pragma unroll
        for (int j = 0; j < 4; ++j) {
            const unsigned uu[4] = {nx[j].x, nx[j].y, nx[j].z, nx[j].w};
            #pragma unroll
            for (int k = 0; k < 8; ++k) {
                const int r = grh*32 + j*8 + k;
                const int byte = (r*512 + gd*2) ^ ((r & 7) << 4);
                *reinterpret_cast<u16*>(xg + byte) =
                    (k & 1) ? (u16)(uu[k >> 1] >> 16) : (u16)(uu[k >> 1] & 0xffffu);
            }
        }
        if (gi < 7) {   // T14: prefetch next group's rows under the MFMA phases
            const int col = idx[(g + 1)*256 + gd];
            const uint4* src = reinterpret_cast<const uint4*>(h1T + (size_t)col*BB + b0 + grh*32);
            #pragma unroll
            for (int j = 0; j < 4; ++j) nx[j] = src[j];
        }
        __syncthreads();

        f32x4 acc[4][2];
        for (int l = 0; l < 2; ++l) {
            const char* A = l ? hb : xg;
            const bf16x8* bp = reinterpret_cast<const bf16x8*>(wpack)
                             + ((size_t)(32 + g*2 + l) * 128 + wv*2) * 64 + lane;
            const float* bg = bias + (g*2 + l) * 256;
            #pragma unroll
            for (int nl = 0; nl < 2; ++nl) {
                const float bv = bg[(wv*2 + nl)*16 + ln15];
                #pragma unroll
                for (int rt = 0; rt < 4; ++rt) acc[rt][nl] = (f32x4){bv, bv, bv, bv};
            }
            bf16x8 bcur[2];
            bcur[0] = bp[0]; bcur[1] = bp[64];
            for (int kt = 0; kt < 8; ++kt) {
                bf16x8 bnext[2];
                if (kt < 7) { bnext[0] = bp[(kt+1)*1024]; bnext[1] = bp[(kt+1)*1024 + 64]; }
                bf16x8 afr[4];
                #pragma unroll
                for (int rt = 0; rt < 4; ++rt) {
                    const int row = rt*16 + ln15;
                    const int byte = (row*512 + kt*64 + lhi*16) ^ ((row & 7) << 4);
                    afr[rt] = *reinterpret_cast<const bf16x8*>(A + byte);
                }
                #pragma unroll
                for (int rt = 0; rt < 4; ++rt) {
                    acc[rt][0] = MFMA16(afr[rt], bcur[0], acc[rt][0]);
                    acc[rt][1] = MFMA16(afr[rt], bcur[1], acc[rt][1]);
                }
                bcur[0] = bnext[0]; bcur[1] = bnext[1];
            }
            if (l == 0) {
                #pragma unroll
                for (int rt = 0; rt < 4; ++rt)
                    #pragma unroll
                    for (int nl = 0; nl < 2; ++nl)
                        #pragma unroll
                        for (int q = 0; q < 4; ++q) {
                            const int row = rt*16 + lhi*4 + q;
                            const int cn  = (wv*2 + nl)*16 + ln15;
                            const int byte = (row*512 + cn*2) ^ ((row & 7) << 4);
                            *reinterpret_cast<u16*>(hb + byte) = f2bf(gelu_f(acc[rt][nl][q]));
                        }
                __syncthreads();
            }
        }
        __syncthreads();   // l=1 hb frag reads done
        #pragma unroll
        for (int rt = 0; rt < 4; ++rt)
            #pragma unroll
            for (int nl = 0; nl < 2; ++nl)
                #pragma unroll
                for (int q = 0; q < 4; ++q) {
                    const int row = rt*16 + lhi*4 + q;
                    const int cn  = (wv*2 + nl)*16 + ln15;
                    const int byte = (row*512 + cn*2) ^ ((row & 7) << 4);
                    const float x = bf2f(*reinterpret_cast<const u16*>(xg + byte));
                    *reinterpret_cast<u16*>(hb + byte) = f2bf(gelu_f(acc[rt][nl][q]) + x);
                }
        __syncthreads();

        // LN + ssr accumulate: row = grow, cols goct*32..+32
        {
            const int rswz = (grow & 7) << 4;
            uint4 raw[4];
            #pragma unroll
            for (int i = 0; i < 4; ++i)
                raw[i] = *reinterpret_cast<const uint4*>(hb + ((grow*512 + goct*64 + i*16) ^ rswz));
            float v[32];
            float s = 0.f;
            #pragma unroll
            for (int i = 0; i < 4; ++i) {
                const unsigned u[4] = {raw[i].x, raw[i].y, raw[i].z, raw[i].w};
                #pragma unroll
                for (int w = 0; w < 4; ++w) {
                    const float a = bf2f((u16)(u[w] & 0xffffu));
                    const float b = bf2f((u16)(u[w] >> 16));
                    v[i*8 + w*2]     = a;
                    v[i*8 + w*2 + 1] = b;
                    s += a + b;
                }
            }
            s += __shfl_xor(s, 1); s += __shfl_xor(s, 2); s += __shfl_xor(s, 4);
            const float mu = s * (1.0f/256.0f);
            float ss = 0.f;
            #pragma unroll
            for (int j = 0; j < 32; ++j) { const float d = v[j] - mu; ss += d*d; }
            ss += __shfl_xor(ss, 1); ss += __shfl_xor(ss, 2); ss += __shfl_xor(ss, 4);
            const float sc = rsqrtf(ss * (1.0f/256.0f) + EPSV);
            const float4* gap = reinterpret_cast<const float4*>(gam + g*256 + goct*32);
            const float4* btp = reinterpret_cast<const float4*>(bet + g*256 + goct*32);
            #pragma unroll
            for (int i = 0; i < 8; ++i) {
                const float4 ga = gap[i], bt = btp[i];
                const float gaa[4] = {ga.x, ga.y, ga.z, ga.w};
                const float bta[4] = {bt.x, bt.y, bt.z, bt.w};
                #pragma unroll
                for (int w = 0; w < 4; ++w)
                    accs[i*4 + w] = fmaf((v[i*4 + w] - mu) * sc * gaa[w] + bta[w],
                                         0.0625f, accs[i*4 + w]);
            }
        }
        // loop-top barrier orders these hb/xg reads vs next gather writes
    }

    // store partial ssr (coalesced float4)
    float* dst = pssr + ((size_t)gset*BB + b0 + grow)*256 + goct*32;
    #pragma unroll
    for (int w = 0; w < 8; ++w)
        reinterpret_cast<float4*>(dst)[w] =
            make_float4(accs[w*4], accs[w*4+1], accs[w*4+2], accs[w*4+3]);
}

// ---------------------------------------------------------------------------
// Kernel 4: head. grid 256, 256 thr. ssr = pssr[0]+pssr[1];
// hid = relu(ssr@Wp1+bp1); out = sigmoid(hid@Wp2+bp2).
// ---------------------------------------------------------------------------
__global__ __launch_bounds__(256)
void head_kernel(const float* __restrict__ pssr,  // [2][BB][256]
                 const float* __restrict__ Wp1,   // [256,64]
                 const float* __restrict__ bp1,
                 const float* __restrict__ Wp2,
                 const float* __restrict__ bp2,
                 float* __restrict__ outp) {
    __shared__ float ssr_s[64 * 256];   // 64KB
    __shared__ float wp1_s[256 * 64];   // 64KB
    const int b0 = blockIdx.x * 64;
    const int t  = threadIdx.x;
    #pragma unroll
    for (int i = 0; i < 16; ++i) {
        const int id = t + i*256;              // float4 id 0..4095
        const int row = id >> 6, c4 = id & 63;
        const float4 a = reinterpret_cast<const float4*>(pssr)[(size_t)(b0 + row)*64 + c4];
        const float4 b = reinterpret_cast<const float4*>(pssr + (size_t)BB*256)[(size_t)(b0 + row)*64 + c4];
        reinterpret_cast<float4*>(ssr_s)[row*64 + c4] =
            make_float4(a.x + b.x, a.y + b.y, a.z + b.z, a.w + b.w);
    }
    #pragma unroll
    for (int i = 0; i < 16; ++i)
        reinterpret_cast<float4*>(wp1_s)[t + i*256] =
            reinterpret_cast<const float4*>(Wp1)[t + i*256];
    __syncthreads();
    const int j = t & 63, rq = t >> 6;
    const float w2j = Wp2[j], b1j = bp1[j], b2v = bp2[0];
    for (int k = 0; k < 16; ++k) {
        const int row = k*4 + rq;
        const float* sr = ssr_s + row*256;
        float s = b1j;
        #pragma unroll 8
        for (int d = 0; d < 256; ++d)
            s = fmaf(sr[d], wp1_s[d*64 + j], s);
        s = fmaxf(s, 0.f) * w2j;
        #pragma unroll
        for (int mm = 1; mm < 64; mm <<= 1) s += __shfl_xor(s, mm);
        if (j == 0) outp[b0 + row] = 1.0f / (1.0f + expf(-(s + b2v)));
    }
}

// ---------------------------------------------------------------------------
extern "C" void kernel_launch(void* const* d_in, const int* in_sizes, int n_in,
                              void* d_out, int out_size, void* d_ws, size_t ws_size,
                              hipStream_t stream) {
    const int*   fidx  = (const int*)  d_in[0];
    const float* fval  = (const float*)d_in[1];
    const float* table = (const float*)d_in[2];
    const float* ge    = (const float*)d_in[3];
    const float* be    = (const float*)d_in[4];
    const int*   idx1  = (const int*)  d_in[5];
    const float* W1    = (const float*)d_in[6];
    const float* b1    = (const float*)d_in[7];
    const float* g1    = (const float*)d_in[8];
    const float* be1   = (const float*)d_in[9];
    const int*   idx2  = (const int*)  d_in[10];
    const float* W2    = (const float*)d_in[11];
    const float* b2    = (const float*)d_in[12];
    const float* g2    = (const float*)d_in[13];
    const float* be2   = (const float*)d_in[14];
    const float* Wp1   = (const float*)d_in[15];
    const float* bp1   = (const float*)d_in[16];
    const float* Wp2   = (const float*)d_in[17];
    const float* bp2   = (const float*)d_in[18];
    float* out = (float*)d_out;

    // ws: wpack 8.4MB | xflatT bf16 [1024][BB] 32MB (overlaid by pssr f32
    // [2][BB][256] 32MB after ssr1) | h1T bf16 [4096][BB] 128MB  (~168MB)
    const size_t wpack_elems = (size_t)64 * 8 * 16 * 64 * 8;
    const size_t need = wpack_elems*2 + (size_t)BB*1024*2 + (size_t)BB*GD*2;
    if (ws_size < need) {
        hipMemsetAsync(d_out, 0, (size_t)out_size * sizeof(float), stream);
        return;
    }
    u16*   wpack = (u16*)d_ws;
    u16*   xT    = wpack + wpack_elems;
    float* pssr  = (float*)xT;                 // overlay (xT dead after ssr1)
    u16*   h1T   = xT + (size_t)BB * 1024;

    prepack_kernel<<<2048, 256, 0, stream>>>(W1, W2, wpack);
    embed_ln_kernel<<<1024, 256, 0, stream>>>(fidx, fval, table, ge, be, xT);
    ssr1_mfma<<<4096, 256, 0, stream>>>(xT, idx1, wpack, b1, g1, be1, h1T);
    ssr2_mfma<<<512, 512, 0, stream>>>(h1T, idx2, wpack, b2, g2, be2, pssr);
    head_kernel<<<256, 256, 0, stream>>>(pssr, Wp1, bp1, Wp2, bp2, out);
}